// Round 12
// baseline (262.182 us; speedup 1.0000x reference)
//
#include <hip/hip_runtime.h>
#include <math.h>

// Shapes: B=3200, L=7, H=8, E=64, S=56, D=64, N=50
// queries [B,7,8,64], keys [B,56,8,64], values [B,56,8,64], mask [50,7,56]
// out [B,7,8,64] fp32.
//
// CROSS-UNIT SOFTWARE PIPELINE (persistent + DMA double-buffer).
// R11 proved DMA staging works but exposed a full K HBM latency per unit
// (~2.7k of ~5.2k cycles) with too few waves to hide it. Here 512
// persistent blocks (2/CU, all resident) each process 50 CONTIGUOUS units;
// while unit u computes from K/V buffers [u&1], the 28 global_load_lds ops
// for unit u+1 stream into buffers [(u+1)&1], and Q/mask for u+1 prefetch
// into registers. All waits are counted (vmcnt(49)) - never a drain.
// Distinct static LDS objects + manual unroll-by-2 keep buffer selection
// compile-time so alias analysis cannot force conservative waits.
// Per-unit compute structure = R11: scores lane=s (K fp32 b128 chunk-XOR
// bank-balanced x Q fp16 uniform broadcast), shuffle softmax (no max-sub,
// scores bounded), P fp32 overlays the read-K buffer, PV lane=d (V b32
// 2-way free x P uniform b128), deferred normalization.

typedef __attribute__((ext_vector_type(8))) _Float16 half8;

#define GLDS(gp, lp) __builtin_amdgcn_global_load_lds(                        \
    (const __attribute__((address_space(1))) void*)(gp),                      \
    (__attribute__((address_space(3))) void*)(lp), 16, 0, 0)

__launch_bounds__(64, 1)
__global__ void fullattn_kernel(const float* __restrict__ q,
                                const float* __restrict__ k,
                                const float* __restrict__ v,
                                const float* __restrict__ mask,
                                float* __restrict__ out,
                                int nstations, int nunits, int nblocks) {
    __shared__ __align__(16) float K0[56 * 64];  // 14336 B each
    __shared__ __align__(16) float K1[56 * 64];
    __shared__ __align__(16) float V0[56 * 64];
    __shared__ __align__(16) float V1[56 * 64];
    __shared__ __align__(16) _Float16 QL[7 * 64];  // 896 B

    const int lane = threadIdx.x;          // 0..63
    const int bid  = blockIdx.x;
    const int ustart = (int)(((long long)bid * nunits) / nblocks);
    const int uend   = (int)(((long long)(bid + 1) * nunits) / nblocks);
    if (ustart >= uend) return;

    const int ml = (lane < 56) ? lane : 55;  // clamped s index
    const int rr = lane >> 4;                // DMA row-within-group
    const int pp = lane & 15;                // DMA slot

    float qr_a[7], m_a[7], qr_b[7], m_b[7];

    // ---- issue K+V DMA for unit u (28 ops, zero VGPR cost) ----
    auto issue_kv = [&](int u, float* KB, float* VB) {
        const int kbase = (u >> 3) * 28672 + (u & 7) * 64;
#pragma unroll
        for (int j = 0; j < 14; ++j) {
            const int row = j * 4 + rr;
            const int c   = pp ^ (row & 15);   // pre-swizzled source chunk
            GLDS(k + kbase + row * 512 + c * 4, (char*)KB + j * 1024);
        }
#pragma unroll
        for (int j = 0; j < 14; ++j) {
            const int row = j * 4 + rr;
            GLDS(v + kbase + row * 512 + pp * 4, (char*)VB + j * 1024);
        }
    };
    // ---- prefetch Q + mask for unit u into registers (14 ops) ----
    auto load_qm = [&](int u, float (&qr)[7], float (&m)[7]) {
        const int qbase = (u >> 3) * 3584 + (u & 7) * 64;
#pragma unroll
        for (int l = 0; l < 7; ++l) qr[l] = q[qbase + l * 512 + lane];
        const int st = (u >> 3) % nstations;
#pragma unroll
        for (int l = 0; l < 7; ++l)
            m[l] = mask[st * 392 + l * 56 + ml] * 0.125f;  // scale=1/sqrt(64)
    };
    // ---- compute unit u from resident buffers ----
    auto compute = [&](int u, float* KB, float* VB,
                       const float (&qr)[7], const float (&m)[7]) {
        // Q -> LDS fp16 (per-wave in-order DS: prior scores already read QL)
#pragma unroll
        for (int l = 0; l < 7; ++l) QL[l * 64 + lane] = (_Float16)qr[l];

        const int x16 = ml & 15;
        float acc[7];
#pragma unroll
        for (int l = 0; l < 7; ++l) acc[l] = 0.0f;

#pragma unroll
        for (int c2 = 0; c2 < 8; ++c2) {
            const float4 kv0 = *(const float4*)(&KB[ml * 64 + (((2 * c2)     ^ x16) << 2)]);
            const float4 kv1 = *(const float4*)(&KB[ml * 64 + (((2 * c2 + 1) ^ x16) << 2)]);
#pragma unroll
            for (int l = 0; l < 7; ++l) {
                const half8 qv = *(const half8*)(&QL[l * 64 + c2 * 8]);  // uniform bcast
                acc[l] = fmaf(kv0.x, (float)qv[0], acc[l]);
                acc[l] = fmaf(kv0.y, (float)qv[1], acc[l]);
                acc[l] = fmaf(kv0.z, (float)qv[2], acc[l]);
                acc[l] = fmaf(kv0.w, (float)qv[3], acc[l]);
                acc[l] = fmaf(kv1.x, (float)qv[4], acc[l]);
                acc[l] = fmaf(kv1.y, (float)qv[5], acc[l]);
                acc[l] = fmaf(kv1.z, (float)qv[6], acc[l]);
                acc[l] = fmaf(kv1.w, (float)qv[7], acc[l]);
            }
        }

        // softmax (no max-subtraction; scores bounded); P overlays KB
        float* pbuf = KB;
        float rdenom[7];
#pragma unroll
        for (int l = 0; l < 7; ++l) {
            const float sc = acc[l] * m[l];
            const float p  = (lane < 56) ? __expf(sc) : 0.0f;
            float sum = p;
#pragma unroll
            for (int off = 32; off >= 1; off >>= 1)
                sum += __shfl_xor(sum, off);
            pbuf[l * 64 + lane] = p;
            rdenom[l] = __builtin_amdgcn_rcpf(sum);
        }

        // PV: lane = d; V b32 (2-way free) x P uniform b128
        float facc[7];
#pragma unroll
        for (int l = 0; l < 7; ++l) facc[l] = 0.0f;
#pragma unroll
        for (int s4 = 0; s4 < 14; ++s4) {
            const float vv0 = VB[(s4 * 4 + 0) * 64 + lane];
            const float vv1 = VB[(s4 * 4 + 1) * 64 + lane];
            const float vv2 = VB[(s4 * 4 + 2) * 64 + lane];
            const float vv3 = VB[(s4 * 4 + 3) * 64 + lane];
#pragma unroll
            for (int l = 0; l < 7; ++l) {
                const float4 p4 = *(const float4*)(&pbuf[l * 64 + s4 * 4]);
                facc[l] = fmaf(p4.x, vv0, facc[l]);
                facc[l] = fmaf(p4.y, vv1, facc[l]);
                facc[l] = fmaf(p4.z, vv2, facc[l]);
                facc[l] = fmaf(p4.w, vv3, facc[l]);
            }
        }

        // epilogue: deferred normalization + coalesced store
        const int qbase = (u >> 3) * 3584 + (u & 7) * 64;
#pragma unroll
        for (int l = 0; l < 7; ++l)
            out[qbase + l * 512 + lane] = facc[l] * rdenom[l];
    };

    // main iteration: prefetch u+1 into write-buffers, counted wait, compute u
    auto main_iter = [&](int u, float* KR, float* VR, float* KW, float* VW,
                         const float (&qc)[7], const float (&mc)[7],
                         float (&qn)[7], float (&mn)[7]) {
        issue_kv(u + 1, KW, VW);
        load_qm(u + 1, qn, mn);
        __builtin_amdgcn_sched_barrier(0);
        // newer-than-unit-u's-loads: prev stores(7) + prefetch(28) + QM(14) = 49
        asm volatile("s_waitcnt vmcnt(49)" ::: "memory");
        __builtin_amdgcn_sched_barrier(0);
        compute(u, KR, VR, qc, mc);
    };
    auto last_iter = [&](int u, float* KR, float* VR,
                         const float (&qc)[7], const float (&mc)[7]) {
        __builtin_amdgcn_sched_barrier(0);
        asm volatile("s_waitcnt vmcnt(7)" ::: "memory");  // prev stores only
        __builtin_amdgcn_sched_barrier(0);
        compute(u, KR, VR, qc, mc);
    };

    // prologue: unit ustart -> K0/V0 + regs A
    issue_kv(ustart, K0, V0);
    load_qm(ustart, qr_a, m_a);

    int u = ustart;
    while (u + 2 < uend) {   // paired mains keep buffer parity compile-time
        main_iter(u,     K0, V0, K1, V1, qr_a, m_a, qr_b, m_b);
        main_iter(u + 1, K1, V1, K0, V0, qr_b, m_b, qr_a, m_a);
        u += 2;
    }
    if (u + 1 < uend) {      // two units left
        main_iter(u, K0, V0, K1, V1, qr_a, m_a, qr_b, m_b);
        last_iter(u + 1, K1, V1, qr_b, m_b);
    } else {                 // one unit left
        last_iter(u, K0, V0, qr_a, m_a);
    }
}

extern "C" void kernel_launch(void* const* d_in, const int* in_sizes, int n_in,
                              void* d_out, int out_size, void* d_ws, size_t ws_size,
                              hipStream_t stream) {
    const float* q    = (const float*)d_in[0];
    const float* k    = (const float*)d_in[1];
    const float* v    = (const float*)d_in[2];
    const float* mask = (const float*)d_in[3];
    float* out        = (float*)d_out;

    const int B = in_sizes[0] / (7 * 8 * 64);        // 3200
    const int nstations = in_sizes[3] / (7 * 56);    // 50
    const int nunits = B * 8;                        // 25600
    const int nblocks = 512;                         // 2/CU, all resident

    fullattn_kernel<<<dim3(nblocks), dim3(64), 0, stream>>>(q, k, v, mask, out,
                                                            nstations, nunits, nblocks);
}

// Round 13
// 162.104 us; speedup vs baseline: 1.6174x; 1.6174x over previous
//
#include <hip/hip_runtime.h>
#include <math.h>

// Shapes: B=3200, L=7, H=8, E=64, S=56, D=64, N=50
// queries [B,7,8,64], keys [B,56,8,64], values [B,56,8,64], mask [50,7,56]
// out [B,7,8,64] fp32.
//
// MFMA PER-UNIT COMPUTE on top of R11's DMA staging (best: 160.6 us).
// scores: D=A.B with A=Q16 (M=16 rows, rows 7-15 clamped), B=K16^T -> 4
// n-tiles x 2 k-chunks of mfma_f32_16x16x32_f16. PV: A=P16, B=V (cvt from
// fp32 VL per-fragment). C layout (m89): row=(lane>>4)*4+reg, col=lane&15.
// A/B frags: lane&15 = row/col, 8 consecutive k at (lane>>4)*8 -> half8
// LDS reads, rows XOR-swizzled ((row&7)<<4 bytes) for bank balance.
// Softmax in C layout: mask*0.125 fold, exp (no max-sub, scores bounded),
// nt-sum + shfl_xor{1,2,4,8} row-sum, rdenom[reg]; P16 written unnormalized,
// normalization deferred to the store (facc rows match rdenom rows).
// DMA: K (chunk-XOR pre-swizzled source) + V (linear) via global_load_lds;
// counted vmcnt(30) lets mask+V fly through the K-cvt and scores.

typedef __attribute__((ext_vector_type(8))) _Float16 half8;
typedef __attribute__((ext_vector_type(4))) _Float16 half4;
typedef __attribute__((ext_vector_type(4))) float floatx4;

#define GLDS(gp, lp) __builtin_amdgcn_global_load_lds(                        \
    (const __attribute__((address_space(1))) void*)(gp),                      \
    (__attribute__((address_space(3))) void*)(lp), 16, 0, 0)

__launch_bounds__(64, 2)
__global__ void fullattn_kernel(const float* __restrict__ q,
                                const float* __restrict__ k,
                                const float* __restrict__ v,
                                const float* __restrict__ mask,
                                float* __restrict__ out,
                                int nstations) {
    __shared__ __align__(16) float    KL[56 * 64];   // 14336 B, DMA dest (swizzled src)
    __shared__ __align__(16) float    VL[56 * 64];   // 14336 B, DMA dest (linear)
    __shared__ __align__(16) _Float16 K16[56 * 64];  // 7168 B, row-XOR swizzled
    __shared__ __align__(16) _Float16 Q16[7 * 64];   // 896 B, row-XOR swizzled
    __shared__ __align__(16) _Float16 P16[16 * 64];  // 2048 B, row-XOR swizzled

    const int lane = threadIdx.x;       // 0..63
    const int unit = blockIdx.x;
    const int b    = unit >> 3;
    const int h    = unit & 7;
    const int st   = b % nstations;

    const int kbase = b * 28672 + h * 64;  // keys/values
    const int qbase = b * 3584  + h * 64;  // queries/out

    const int rr  = lane >> 4;   // k-group / DMA row-in-group
    const int col = lane & 15;   // frag row/col index / DMA slot

    // ---- group 1: K DMA (chunk-XOR pre-swizzled source) ----
#pragma unroll
    for (int j = 0; j < 14; ++j) {
        const int row  = j * 4 + rr;
        const int csrc = col ^ (row & 15);
        GLDS(k + kbase + row * 512 + csrc * 4, (char*)KL + j * 1024);
    }
    __builtin_amdgcn_sched_barrier(0);

    // ---- group 2: Q (7 dwords, e = lane) ----
    float qr[7];
#pragma unroll
    for (int l = 0; l < 7; ++l) qr[l] = q[qbase + l * 512 + lane];
    __builtin_amdgcn_sched_barrier(0);

    // ---- group 3: mask in C layout (16 dwords), pre-scaled ----
    float mm[4][4];
#pragma unroll
    for (int nt = 0; nt < 4; ++nt)
#pragma unroll
        for (int reg = 0; reg < 4; ++reg) {
            const int mrow = (rr * 4 + reg < 7) ? (rr * 4 + reg) : 6;
            const int mcol = (col + 16 * nt < 56) ? (col + 16 * nt) : 55;
            mm[nt][reg] = mask[st * 392 + mrow * 56 + mcol] * 0.125f;
        }
    __builtin_amdgcn_sched_barrier(0);

    // ---- group 4: V DMA (linear) ----
#pragma unroll
    for (int j = 0; j < 14; ++j) {
        const int row = j * 4 + rr;
        GLDS(v + kbase + row * 512 + col * 4, (char*)VL + j * 1024);
    }
    __builtin_amdgcn_sched_barrier(0);

    // ---- K + Q landed (mask 16 + V 14 = 30 newer stay in flight) ----
    asm volatile("s_waitcnt vmcnt(30)" ::: "memory");
    __builtin_amdgcn_sched_barrier(0);

    // ---- Q -> Q16 (row-XOR swizzled halves) ----
#pragma unroll
    for (int l = 0; l < 7; ++l)
        Q16[l * 64 + (lane ^ ((l & 7) << 3))] = (_Float16)qr[l];

    // ---- K cvt pass: fp32 (physical slot lc^(s&15)) -> fp16 swizzled ----
#pragma unroll
    for (int i = 0; i < 14; ++i) {
        const int f  = i * 64 + lane;
        const int s  = f >> 4;
        const int lc = f & 15;
        const floatx4 a = *(const floatx4*)(&KL[s * 64 + ((lc ^ (s & 15)) << 2)]);
        half4 hv;
        hv[0] = (_Float16)a[0]; hv[1] = (_Float16)a[1];
        hv[2] = (_Float16)a[2]; hv[3] = (_Float16)a[3];
        *(half4*)(&K16[s * 64 + ((lc << 2) ^ ((s & 7) << 3))]) = hv;
    }

    // ---- scores: 2 k-chunks x 4 n-tiles of mfma 16x16x32 f16 ----
    floatx4 acc[4] = {{0.f,0.f,0.f,0.f},{0.f,0.f,0.f,0.f},
                      {0.f,0.f,0.f,0.f},{0.f,0.f,0.f,0.f}};
    const int qrow = (col < 7) ? col : 0;  // A rows 7-15 -> row 0 (discarded)
#pragma unroll
    for (int kc = 0; kc < 2; ++kc) {
        const int koff = kc * 32 + rr * 8;
        const half8 af = *(const half8*)(&Q16[qrow * 64 + (koff ^ ((qrow & 7) << 3))]);
#pragma unroll
        for (int nt = 0; nt < 4; ++nt) {
            const int sr = (col + 16 * nt < 56) ? (col + 16 * nt) : 55;  // cols 56-63 dead
            const half8 bf = *(const half8*)(&K16[sr * 64 + (koff ^ ((sr & 7) << 3))]);
            acc[nt] = __builtin_amdgcn_mfma_f32_16x16x32_f16(af, bf, acc[nt], 0, 0, 0);
        }
    }

    // ---- softmax in C layout; P16 written unnormalized ----
    float rden[4];
#pragma unroll
    for (int reg = 0; reg < 4; ++reg) {
        float s_r = 0.0f;
        const int prow = rr * 4 + reg;
#pragma unroll
        for (int nt = 0; nt < 4; ++nt) {
            const float sc = acc[nt][reg] * mm[nt][reg];
            float p = __expf(sc);
            if (nt == 3 && (lane & 8)) p = 0.0f;   // cols 56-63
            P16[prow * 64 + ((col + 16 * nt) ^ ((prow & 7) << 3))] = (_Float16)p;
            s_r += p;
        }
#pragma unroll
        for (int off = 1; off <= 8; off <<= 1)
            s_r += __shfl_xor(s_r, off);
        rden[reg] = __builtin_amdgcn_rcpf(s_r);
    }

    // ---- V landed ----
    asm volatile("s_waitcnt vmcnt(0)" ::: "memory");
    __builtin_amdgcn_sched_barrier(0);

    // ---- PV: A=P16, B=V (cvt fp32 VL per fragment) ----
    floatx4 facc[4] = {{0.f,0.f,0.f,0.f},{0.f,0.f,0.f,0.f},
                       {0.f,0.f,0.f,0.f},{0.f,0.f,0.f,0.f}};
#pragma unroll
    for (int kc = 0; kc < 2; ++kc) {
        const int koff = kc * 32 + rr * 8;
        const half8 paf = *(const half8*)(&P16[col * 64 + (koff ^ ((col & 7) << 3))]);
#pragma unroll
        for (int nt = 0; nt < 4; ++nt) {
            half8 vbf;
#pragma unroll
            for (int jj = 0; jj < 8; ++jj) {
                const int sidx = (koff + jj < 56) ? (koff + jj) : 55;  // P=0 there
                vbf[jj] = (_Float16)VL[sidx * 64 + col + 16 * nt];
            }
            facc[nt] = __builtin_amdgcn_mfma_f32_16x16x32_f16(paf, vbf, facc[nt], 0, 0, 0);
        }
    }

    // ---- epilogue: deferred normalization + predicated stores ----
#pragma unroll
    for (int nt = 0; nt < 4; ++nt)
#pragma unroll
        for (int reg = 0; reg < 4; ++reg) {
            const int orow = rr * 4 + reg;
            if (orow < 7)
                out[qbase + orow * 512 + col + 16 * nt] = facc[nt][reg] * rden[reg];
        }
}

extern "C" void kernel_launch(void* const* d_in, const int* in_sizes, int n_in,
                              void* d_out, int out_size, void* d_ws, size_t ws_size,
                              hipStream_t stream) {
    const float* q    = (const float*)d_in[0];
    const float* k    = (const float*)d_in[1];
    const float* v    = (const float*)d_in[2];
    const float* mask = (const float*)d_in[3];
    float* out        = (float*)d_out;

    const int B = in_sizes[0] / (7 * 8 * 64);        // 3200
    const int nstations = in_sizes[3] / (7 * 56);    // 50

    fullattn_kernel<<<dim3(B * 8), dim3(64), 0, stream>>>(q, k, v, mask, out, nstations);
}